// Round 1
// baseline (410.497 us; speedup 1.0000x reference)
//
#include <hip/hip_runtime.h>
#include <math.h>

typedef __bf16 bf16x8 __attribute__((ext_vector_type(8)));
typedef float f32x4 __attribute__((ext_vector_type(4)));

#define B_ 4
#define S_ 1024
#define D_ 768
#define F_ 3072
#define E_ 8
#define NTOK 4096
#define NSLOTP 9216   // 8192 slots + per-expert pad to 128

__device__ __forceinline__ void gload_lds16(const void* g, void* s) {
  __builtin_amdgcn_global_load_lds((const __attribute__((address_space(1))) void*)g,
                                   (__attribute__((address_space(3))) void*)s, 16, 0, 0);
}

// ---------------- router: fp32 logits, softmax, top-2, renorm ----------------
__global__ __launch_bounds__(256) void k_router(const float* __restrict__ x,
    const float* __restrict__ wr, int* __restrict__ tki, float* __restrict__ tkw,
    int* __restrict__ cnt) {
  int wid = threadIdx.x >> 6, lane = threadIdx.x & 63;
  int t = blockIdx.x * 4 + wid;
  const float* xp = x + (size_t)t * D_;
  float pa[E_];
#pragma unroll
  for (int e = 0; e < E_; ++e) pa[e] = 0.f;
#pragma unroll
  for (int it = 0; it < D_ / 64; ++it) {
    int d = it * 64 + lane;
    float xv = xp[d];
    const float4* wp = (const float4*)(wr + (size_t)d * E_);
    float4 a = wp[0], b = wp[1];
    pa[0] += xv * a.x; pa[1] += xv * a.y; pa[2] += xv * a.z; pa[3] += xv * a.w;
    pa[4] += xv * b.x; pa[5] += xv * b.y; pa[6] += xv * b.z; pa[7] += xv * b.w;
  }
#pragma unroll
  for (int e = 0; e < E_; ++e) {
    float v = pa[e];
    for (int off = 32; off; off >>= 1) v += __shfl_xor(v, off);
    pa[e] = v;
  }
  if (lane == 0) {
    float m = pa[0];
#pragma unroll
    for (int e = 1; e < E_; ++e) m = fmaxf(m, pa[e]);
    float p[E_], s = 0.f;
#pragma unroll
    for (int e = 0; e < E_; ++e) { p[e] = expf(pa[e] - m); s += p[e]; }
#pragma unroll
    for (int e = 0; e < E_; ++e) p[e] = p[e] / s;
    int i0 = 0; float b0 = p[0];
#pragma unroll
    for (int e = 1; e < E_; ++e) if (p[e] > b0) { b0 = p[e]; i0 = e; }
    int i1 = -1; float b1v = -1.f;
#pragma unroll
    for (int e = 0; e < E_; ++e) if (e != i0 && p[e] > b1v) { b1v = p[e]; i1 = e; }
    float den = b0 + b1v + 1e-8f;
    tki[t * 2] = i0; tki[t * 2 + 1] = i1;
    tkw[t * 2] = b0 / den; tkw[t * 2 + 1] = b1v / den;
    atomicAdd(&cnt[i0], 1); atomicAdd(&cnt[i1], 1);
  }
}

// -------- scan: per-expert offsets, segments padded to 128 rows --------
__global__ void k_scan(const int* __restrict__ cnt, int* __restrict__ aoff) {
  if (threadIdx.x == 0 && blockIdx.x == 0) {
    int a = 0; aoff[0] = 0;
    for (int e = 0; e < E_; ++e) { a += ((cnt[e] + 127) >> 7) << 7; aoff[e + 1] = a; }
  }
}

// -------- build slot lists (order within expert irrelevant) --------
__global__ __launch_bounds__(256) void k_build(const int* __restrict__ tki,
    const float* __restrict__ tkw, const int* __restrict__ aoff, int* __restrict__ cur,
    int* __restrict__ stok, float* __restrict__ sw) {
  int t = blockIdx.x * 256 + threadIdx.x;
#pragma unroll
  for (int k = 0; k < 2; ++k) {
    int e = tki[t * 2 + k];
    int pos = atomicAdd(&cur[e], 1);
    int s = aoff[e] + pos;
    stok[s] = t; sw[s] = tkw[t * 2 + k];
  }
}

// -------- gather x rows into bf16 slot matrix (zeros for padding) --------
__global__ __launch_bounds__(256) void k_gather(const float* __restrict__ x,
    const int* __restrict__ stok, __bf16* __restrict__ Xg) {
  int i8 = blockIdx.x * 256 + threadIdx.x;      // 8-element group index
  int flat = i8 * 8;
  int row = flat / D_;
  int col = flat - row * D_;
  int tok = stok[row];
  bf16x8 v;
  if (tok >= 0) {
    const float4* s = (const float4*)(x + (size_t)tok * D_ + col);
    float4 a = s[0], b = s[1];
    v[0] = (__bf16)a.x; v[1] = (__bf16)a.y; v[2] = (__bf16)a.z; v[3] = (__bf16)a.w;
    v[4] = (__bf16)b.x; v[5] = (__bf16)b.y; v[6] = (__bf16)b.z; v[7] = (__bf16)b.w;
  } else {
#pragma unroll
    for (int k = 0; k < 8; ++k) v[k] = (__bf16)0.f;
  }
  *(bf16x8*)(Xg + (size_t)flat) = v;
}

// -------- fp32 [R][C] -> bf16 [C][R] per expert, LDS-tiled --------
__global__ __launch_bounds__(256) void k_transpose(const float* __restrict__ in,
    __bf16* __restrict__ outp, int R, int C) {
  __shared__ __bf16 T[64][65];
  int e = blockIdx.z;
  int r0 = blockIdx.y * 64, c0 = blockIdx.x * 64;
  const float* ip = in + (size_t)e * R * C;
  int rl = threadIdx.x >> 2, q0 = (threadIdx.x & 3) * 16;
  const float4* src = (const float4*)(ip + (size_t)(r0 + rl) * C + c0 + q0);
#pragma unroll
  for (int q = 0; q < 4; ++q) {
    float4 v = src[q];
    T[rl][q0 + q * 4 + 0] = (__bf16)v.x;
    T[rl][q0 + q * 4 + 1] = (__bf16)v.y;
    T[rl][q0 + q * 4 + 2] = (__bf16)v.z;
    T[rl][q0 + q * 4 + 3] = (__bf16)v.w;
  }
  __syncthreads();
  __bf16* op = outp + (size_t)e * R * C + (size_t)(c0 + rl) * R + r0 + q0;
  bf16x8 v0, v1;
#pragma unroll
  for (int i = 0; i < 8; ++i) { v0[i] = T[q0 + i][rl]; v1[i] = T[q0 + 8 + i][rl]; }
  *(bf16x8*)(op) = v0;
  *(bf16x8*)(op + 8) = v1;
}

// -------- grouped GEMM: 128x128 tile, BK=32, 4 waves of 64x64 --------
// MODE 0: H = gelu(Xg @ w1t^T + b1)   [NSLOTP][F]
// MODE 1: out[token] += sw * (H @ w2t^T + b2)  (atomic)
template<int K, int N, int MODE>
__global__ __launch_bounds__(256) void k_gemm(
    const __bf16* __restrict__ A, const __bf16* __restrict__ Bt,
    const float* __restrict__ bias, const int* __restrict__ aoff,
    const int* __restrict__ stok, const float* __restrict__ sw,
    __bf16* __restrict__ Hout, float* __restrict__ out) {
  __shared__ __align__(16) __bf16 Al[128 * 32];
  __shared__ __align__(16) __bf16 Bl[128 * 32];
  int nb = blockIdx.x, mb = blockIdx.y;
  int row0 = mb * 128;
  if (row0 >= aoff[E_]) return;
  int e = 0;
#pragma unroll
  for (int q = 0; q < E_; ++q) if (row0 >= aoff[q + 1]) e = q + 1;
  const __bf16* Bp = Bt + (size_t)e * D_ * F_;
  int tid = threadIdx.x, w = tid >> 6, l = tid & 63;
  int lr = l >> 2, ls = l & 3;      // staging: row-in-group / 16B slot
  int fr = l & 15, fg = l >> 4;     // fragment: row-col / k-group
  f32x4 acc[4][4] = {};
  int wrow = (w >> 1) * 64, wcol = (w & 1) * 64;
  for (int kt = 0; kt < K / 32; ++kt) {
    int k0 = kt * 32;
#pragma unroll
    for (int q = 0; q < 2; ++q) {
      int rl = (w * 2 + q) * 16 + lr;                 // 0..127 tile row
      int slot = ls ^ ((rl >> 1) & 3);                // pre-swizzled source chunk
      gload_lds16(A + (size_t)(row0 + rl) * K + k0 + slot * 8, Al + (w * 2 + q) * 512);
      gload_lds16(Bp + (size_t)(nb * 128 + rl) * K + k0 + slot * 8, Bl + (w * 2 + q) * 512);
    }
    __syncthreads();
    bf16x8 af[4], bfr[4];
#pragma unroll
    for (int i = 0; i < 4; ++i) {
      int rl = wrow + i * 16 + fr;
      af[i] = *(const bf16x8*)(Al + rl * 32 + ((fg ^ ((rl >> 1) & 3)) << 3));
    }
#pragma unroll
    for (int j = 0; j < 4; ++j) {
      int nl = wcol + j * 16 + fr;
      bfr[j] = *(const bf16x8*)(Bl + nl * 32 + ((fg ^ ((nl >> 1) & 3)) << 3));
    }
#pragma unroll
    for (int i = 0; i < 4; ++i)
#pragma unroll
      for (int j = 0; j < 4; ++j)
        acc[i][j] = __builtin_amdgcn_mfma_f32_16x16x32_bf16(af[i], bfr[j], acc[i][j], 0, 0, 0);
    __syncthreads();
  }
  if constexpr (MODE == 0) {
#pragma unroll
    for (int j = 0; j < 4; ++j) {
      int col = nb * 128 + wcol + j * 16 + fr;
      float bv = bias[e * N + col];
#pragma unroll
      for (int i = 0; i < 4; ++i) {
#pragma unroll
        for (int r = 0; r < 4; ++r) {
          int row = row0 + wrow + i * 16 + fg * 4 + r;
          float v = acc[i][j][r] + bv;
          v = 0.5f * v * (1.f + erff(v * 0.7071067811865475f));
          Hout[(size_t)row * N + col] = (__bf16)v;
        }
      }
    }
  } else {
#pragma unroll
    for (int i = 0; i < 4; ++i) {
#pragma unroll
      for (int r = 0; r < 4; ++r) {
        int row = row0 + wrow + i * 16 + fg * 4 + r;
        int tok = stok[row];
        if (tok < 0) continue;
        float scale = sw[row];
#pragma unroll
        for (int j = 0; j < 4; ++j) {
          int col = nb * 128 + wcol + j * 16 + fr;
          float v = acc[i][j][r] + bias[e * N + col];
          atomicAdd(out + (size_t)tok * D_ + col, scale * v);
        }
      }
    }
  }
}

extern "C" void kernel_launch(void* const* d_in, const int* in_sizes, int n_in,
                              void* d_out, int out_size, void* d_ws, size_t ws_size,
                              hipStream_t stream) {
  const float* x  = (const float*)d_in[0];
  const float* wr = (const float*)d_in[1];
  const float* w1 = (const float*)d_in[2];
  const float* b1 = (const float*)d_in[3];
  const float* w2 = (const float*)d_in[4];
  const float* b2 = (const float*)d_in[5];
  float* out = (float*)d_out;

  char* ws = (char*)d_ws;
  size_t o = 0;
  __bf16* w1t = (__bf16*)(ws + o); o += (size_t)E_ * D_ * F_ * 2;   // [E][F][D]
  __bf16* w2t = (__bf16*)(ws + o); o += (size_t)E_ * D_ * F_ * 2;   // [E][D][F]
  __bf16* Xg  = (__bf16*)(ws + o); o += (size_t)NSLOTP * D_ * 2;    // [NSLOTP][D]
  __bf16* H   = (__bf16*)(ws + o); o += (size_t)NSLOTP * F_ * 2;    // [NSLOTP][F]
  int*   tki  = (int*)(ws + o);   o += (size_t)NTOK * 2 * 4;
  float* tkw  = (float*)(ws + o); o += (size_t)NTOK * 2 * 4;
  int*   stok = (int*)(ws + o);   o += (size_t)NSLOTP * 4;
  float* sw   = (float*)(ws + o); o += (size_t)NSLOTP * 4;
  int*   cnt  = (int*)(ws + o);   o += 32;
  int*   cur  = (int*)(ws + o);   o += 32;
  int*   aoff = (int*)(ws + o);   o += 64;
  if (ws_size < o) return;  // ws too small -> leaves out poisoned (signature absmax ~1.42)

  hipMemsetAsync(d_out, 0, (size_t)NTOK * D_ * 4, stream);
  hipMemsetAsync(cnt, 0, 64, stream);                 // cnt + cur
  hipMemsetAsync(stok, 0xFF, (size_t)NSLOTP * 4, stream);  // -1

  k_router<<<NTOK / 4, 256, 0, stream>>>(x, wr, tki, tkw, cnt);
  k_scan<<<1, 64, 0, stream>>>(cnt, aoff);
  k_build<<<NTOK / 256, 256, 0, stream>>>(tki, tkw, aoff, cur, stok, sw);
  k_gather<<<(NSLOTP * D_ / 8) / 256, 256, 0, stream>>>(x, stok, Xg);
  k_transpose<<<dim3(F_ / 64, D_ / 64, E_), 256, 0, stream>>>(w1, w1t, D_, F_);
  k_transpose<<<dim3(D_ / 64, F_ / 64, E_), 256, 0, stream>>>(w2, w2t, F_, D_);
  k_gemm<D_, F_, 0><<<dim3(F_ / 128, NSLOTP / 128), 256, 0, stream>>>(
      Xg, w1t, b1, aoff, stok, sw, H, nullptr);
  k_gemm<F_, D_, 1><<<dim3(D_ / 128, NSLOTP / 128), 256, 0, stream>>>(
      H, w2t, b2, aoff, stok, sw, nullptr, out);
}

// Round 2
// 349.925 us; speedup vs baseline: 1.1731x; 1.1731x over previous
//
#include <hip/hip_runtime.h>
#include <math.h>

typedef __bf16 bf16x8 __attribute__((ext_vector_type(8)));
typedef float f32x4 __attribute__((ext_vector_type(4)));

#define B_ 4
#define S_ 1024
#define D_ 768
#define F_ 3072
#define E_ 8
#define NTOK 4096
#define NSLOTP 9216   // 8192 slots + per-expert pad to 128

__device__ __forceinline__ void gload_lds16(const void* g, void* s) {
  __builtin_amdgcn_global_load_lds((const __attribute__((address_space(1))) void*)g,
                                   (__attribute__((address_space(3))) void*)s, 16, 0, 0);
}

__device__ __forceinline__ float gelu_f(float v) {
  // tanh-form gelu; |err| vs erf-form ~1e-3, negligible after W2 contraction
  float u = v * (0.7978845608f + 0.0356774081f * v * v);
  float t = 1.f - 2.f / (1.f + __expf(2.f * u));   // overflow -> t=1, underflow -> t=-1 (correct limits)
  return 0.5f * v * (1.f + t);
}

// ---------------- router: fp32 logits, softmax, top-2, renorm ----------------
__global__ __launch_bounds__(256) void k_router(const float* __restrict__ x,
    const float* __restrict__ wr, int* __restrict__ tki, float* __restrict__ tkw,
    int* __restrict__ cnt) {
  int wid = threadIdx.x >> 6, lane = threadIdx.x & 63;
  int t = blockIdx.x * 4 + wid;
  const float* xp = x + (size_t)t * D_;
  float pa[E_];
#pragma unroll
  for (int e = 0; e < E_; ++e) pa[e] = 0.f;
#pragma unroll
  for (int it = 0; it < D_ / 64; ++it) {
    int d = it * 64 + lane;
    float xv = xp[d];
    const float4* wp = (const float4*)(wr + (size_t)d * E_);
    float4 a = wp[0], b = wp[1];
    pa[0] += xv * a.x; pa[1] += xv * a.y; pa[2] += xv * a.z; pa[3] += xv * a.w;
    pa[4] += xv * b.x; pa[5] += xv * b.y; pa[6] += xv * b.z; pa[7] += xv * b.w;
  }
#pragma unroll
  for (int e = 0; e < E_; ++e) {
    float v = pa[e];
    for (int off = 32; off; off >>= 1) v += __shfl_xor(v, off);
    pa[e] = v;
  }
  if (lane == 0) {
    float m = pa[0];
#pragma unroll
    for (int e = 1; e < E_; ++e) m = fmaxf(m, pa[e]);
    float p[E_], s = 0.f;
#pragma unroll
    for (int e = 0; e < E_; ++e) { p[e] = expf(pa[e] - m); s += p[e]; }
#pragma unroll
    for (int e = 0; e < E_; ++e) p[e] = p[e] / s;
    int i0 = 0; float b0 = p[0];
#pragma unroll
    for (int e = 1; e < E_; ++e) if (p[e] > b0) { b0 = p[e]; i0 = e; }
    int i1 = -1; float b1v = -1.f;
#pragma unroll
    for (int e = 0; e < E_; ++e) if (e != i0 && p[e] > b1v) { b1v = p[e]; i1 = e; }
    float den = b0 + b1v + 1e-8f;
    tki[t * 2] = i0; tki[t * 2 + 1] = i1;
    tkw[t * 2] = b0 / den; tkw[t * 2 + 1] = b1v / den;
    atomicAdd(&cnt[i0], 1); atomicAdd(&cnt[i1], 1);
  }
}

// -------- scan: per-expert offsets, segments padded to 128 rows --------
__global__ void k_scan(const int* __restrict__ cnt, int* __restrict__ aoff) {
  if (threadIdx.x == 0 && blockIdx.x == 0) {
    int a = 0; aoff[0] = 0;
    for (int e = 0; e < E_; ++e) { a += ((cnt[e] + 127) >> 7) << 7; aoff[e + 1] = a; }
  }
}

// -------- build slot lists + inverse map --------
__global__ __launch_bounds__(256) void k_build(const int* __restrict__ tki,
    const float* __restrict__ tkw, const int* __restrict__ aoff, int* __restrict__ cur,
    int* __restrict__ stok, int* __restrict__ tslot) {
  int t = blockIdx.x * 256 + threadIdx.x;
#pragma unroll
  for (int k = 0; k < 2; ++k) {
    int e = tki[t * 2 + k];
    int pos = atomicAdd(&cur[e], 1);
    int s = aoff[e] + pos;
    stok[s] = t;
    tslot[t * 2 + k] = s;
  }
}

// -------- gather x rows into bf16 slot matrix (zeros for padding) --------
__global__ __launch_bounds__(256) void k_gather(const float* __restrict__ x,
    const int* __restrict__ stok, __bf16* __restrict__ Xg) {
  int i8 = blockIdx.x * 256 + threadIdx.x;
  int flat = i8 * 8;
  int row = flat / D_;
  int col = flat - row * D_;
  int tok = stok[row];
  bf16x8 v;
  if (tok >= 0) {
    const float4* s = (const float4*)(x + (size_t)tok * D_ + col);
    float4 a = s[0], b = s[1];
    v[0] = (__bf16)a.x; v[1] = (__bf16)a.y; v[2] = (__bf16)a.z; v[3] = (__bf16)a.w;
    v[4] = (__bf16)b.x; v[5] = (__bf16)b.y; v[6] = (__bf16)b.z; v[7] = (__bf16)b.w;
  } else {
#pragma unroll
    for (int k = 0; k < 8; ++k) v[k] = (__bf16)0.f;
  }
  *(bf16x8*)(Xg + (size_t)flat) = v;
}

// -------- fp32 [R][C] -> bf16 [C][R] per expert; fp32 LDS tile, 2-way-free banks --------
__global__ __launch_bounds__(256) void k_transpose(const float* __restrict__ in,
    __bf16* __restrict__ outp, int R, int C) {
  __shared__ float Ts[64][65];
  int e = blockIdx.z;
  int r0 = blockIdx.y * 64, c0 = blockIdx.x * 64;
  const float* ip = in + (size_t)e * R * C;
  int lr = threadIdx.x >> 4;          // 0..15
  int lc = (threadIdx.x & 15) * 4;    // 0..60
#pragma unroll
  for (int it = 0; it < 4; ++it) {
    int r = lr + it * 16;
    float4 v = *(const float4*)(ip + (size_t)(r0 + r) * C + c0 + lc);
    Ts[r][lc] = v.x; Ts[r][lc + 1] = v.y; Ts[r][lc + 2] = v.z; Ts[r][lc + 3] = v.w;
  }
  __syncthreads();
  int rr = (threadIdx.x & 7) * 8;     // 0..56
  int cc = threadIdx.x >> 3;          // 0..31
  __bf16* op = outp + (size_t)e * R * C + r0 + rr;
#pragma unroll
  for (int it = 0; it < 2; ++it) {
    int c = cc + it * 32;
    bf16x8 v;
#pragma unroll
    for (int i = 0; i < 8; ++i) v[i] = (__bf16)Ts[rr + i][c];
    *(bf16x8*)(op + (size_t)(c0 + c) * R) = v;
  }
}

// -------- grouped GEMM: 128x128 tile, BK=32, 4 waves of 64x64, XCD swizzle --------
// MODE 0: H = gelu(Xg @ w1t^T + b1)        [NSLOTP][F]
// MODE 1: Eout = H @ w2t^T + b2  (fp32)    [NSLOTP][D]
template<int K, int N, int MODE>
__global__ __launch_bounds__(256) void k_gemm(
    const __bf16* __restrict__ A, const __bf16* __restrict__ Bt,
    const float* __restrict__ bias, const int* __restrict__ aoff,
    __bf16* __restrict__ Hout, float* __restrict__ Eout) {
  __shared__ __align__(16) __bf16 Al[128 * 32];
  __shared__ __align__(16) __bf16 Bl[128 * 32];
  constexpr int NB = N / 128;
  constexpr int NWG = NB * (NSLOTP / 128);
  int bswz = (blockIdx.x & 7) * (NWG / 8) + (blockIdx.x >> 3);   // XCD-contiguous
  int mb = bswz / NB, nb = bswz % NB;
  int row0 = mb * 128;
  if (row0 >= aoff[E_]) return;
  int e = 0;
#pragma unroll
  for (int q = 0; q < E_; ++q) if (row0 >= aoff[q + 1]) e = q + 1;
  const __bf16* Bp = Bt + (size_t)e * D_ * F_;
  int tid = threadIdx.x, w = tid >> 6, l = tid & 63;
  int lr = l >> 2, ls = l & 3;      // staging: row-in-group / 16B slot
  int fr = l & 15, fg = l >> 4;     // fragment: row-col / k-group
  f32x4 acc[4][4] = {};
  int wrow = (w >> 1) * 64, wcol = (w & 1) * 64;
  for (int kt = 0; kt < K / 32; ++kt) {
    int k0 = kt * 32;
#pragma unroll
    for (int q = 0; q < 2; ++q) {
      int rl = (w * 2 + q) * 16 + lr;
      int slot = ls ^ ((rl >> 1) & 3);
      gload_lds16(A + (size_t)(row0 + rl) * K + k0 + slot * 8, Al + (w * 2 + q) * 512);
      gload_lds16(Bp + (size_t)(nb * 128 + rl) * K + k0 + slot * 8, Bl + (w * 2 + q) * 512);
    }
    __syncthreads();
    bf16x8 af[4], bfr[4];
#pragma unroll
    for (int i = 0; i < 4; ++i) {
      int rl = wrow + i * 16 + fr;
      af[i] = *(const bf16x8*)(Al + rl * 32 + ((fg ^ ((rl >> 1) & 3)) << 3));
    }
#pragma unroll
    for (int j = 0; j < 4; ++j) {
      int nl = wcol + j * 16 + fr;
      bfr[j] = *(const bf16x8*)(Bl + nl * 32 + ((fg ^ ((nl >> 1) & 3)) << 3));
    }
#pragma unroll
    for (int i = 0; i < 4; ++i)
#pragma unroll
      for (int j = 0; j < 4; ++j)
        acc[i][j] = __builtin_amdgcn_mfma_f32_16x16x32_bf16(af[i], bfr[j], acc[i][j], 0, 0, 0);
    __syncthreads();
  }
  if constexpr (MODE == 0) {
#pragma unroll
    for (int j = 0; j < 4; ++j) {
      int col = nb * 128 + wcol + j * 16 + fr;
      float bv = bias[e * N + col];
#pragma unroll
      for (int i = 0; i < 4; ++i) {
#pragma unroll
        for (int r = 0; r < 4; ++r) {
          int row = row0 + wrow + i * 16 + fg * 4 + r;
          Hout[(size_t)row * N + col] = (__bf16)gelu_f(acc[i][j][r] + bv);
        }
      }
    }
  } else {
#pragma unroll
    for (int j = 0; j < 4; ++j) {
      int col = nb * 128 + wcol + j * 16 + fr;
      float bv = bias[e * N + col];
#pragma unroll
      for (int i = 0; i < 4; ++i) {
#pragma unroll
        for (int r = 0; r < 4; ++r) {
          int row = row0 + wrow + i * 16 + fg * 4 + r;
          Eout[(size_t)row * N + col] = acc[i][j][r] + bv;
        }
      }
    }
  }
}

// -------- combine: out[t] = w0*Eout[s0] + w1*Eout[s1] --------
__global__ __launch_bounds__(256) void k_combine(const float* __restrict__ Eout,
    const int* __restrict__ tslot, const float* __restrict__ tkw, float* __restrict__ out) {
  int idx = blockIdx.x * 256 + threadIdx.x;          // per float4
  int t = idx / (D_ / 4);
  int c4 = (idx - t * (D_ / 4)) * 4;
  int s0 = tslot[2 * t], s1 = tslot[2 * t + 1];
  float w0 = tkw[2 * t], w1 = tkw[2 * t + 1];
  float4 a = *(const float4*)(Eout + (size_t)s0 * D_ + c4);
  float4 b = *(const float4*)(Eout + (size_t)s1 * D_ + c4);
  float4 o;
  o.x = w0 * a.x + w1 * b.x; o.y = w0 * a.y + w1 * b.y;
  o.z = w0 * a.z + w1 * b.z; o.w = w0 * a.w + w1 * b.w;
  *(float4*)(out + (size_t)t * D_ + c4) = o;
}

extern "C" void kernel_launch(void* const* d_in, const int* in_sizes, int n_in,
                              void* d_out, int out_size, void* d_ws, size_t ws_size,
                              hipStream_t stream) {
  const float* x  = (const float*)d_in[0];
  const float* wr = (const float*)d_in[1];
  const float* w1 = (const float*)d_in[2];
  const float* b1 = (const float*)d_in[3];
  const float* w2 = (const float*)d_in[4];
  const float* b2 = (const float*)d_in[5];
  float* out = (float*)d_out;

  char* ws = (char*)d_ws;
  size_t o = 0;
  __bf16* w1t = (__bf16*)(ws + o); o += (size_t)E_ * D_ * F_ * 2;   // [E][F][D]; dead after GEMM1
  __bf16* w2t = (__bf16*)(ws + o); o += (size_t)E_ * D_ * F_ * 2;   // [E][D][F]
  __bf16* Xg  = (__bf16*)(ws + o); o += (size_t)NSLOTP * D_ * 2;    // [NSLOTP][D]
  __bf16* H   = (__bf16*)(ws + o); o += (size_t)NSLOTP * F_ * 2;    // [NSLOTP][F]
  int*   tki  = (int*)(ws + o);   o += (size_t)NTOK * 2 * 4;
  float* tkw  = (float*)(ws + o); o += (size_t)NTOK * 2 * 4;
  int*   stok = (int*)(ws + o);   o += (size_t)NSLOTP * 4;
  int*   tslot= (int*)(ws + o);   o += (size_t)NTOK * 2 * 4;
  int*   cnt  = (int*)(ws + o);   o += 32;
  int*   cur  = (int*)(ws + o);   o += 32;
  int*   aoff = (int*)(ws + o);   o += 64;
  float* Eout = (float*)w1t;      // alias: w1t (37.7MB) is dead before GEMM2 writes Eout (28.3MB)
  if (ws_size < o) return;

  hipMemsetAsync(cnt, 0, 64, stream);                       // cnt + cur
  hipMemsetAsync(stok, 0xFF, (size_t)NSLOTP * 4, stream);   // -1

  k_router<<<NTOK / 4, 256, 0, stream>>>(x, wr, tki, tkw, cnt);
  k_scan<<<1, 64, 0, stream>>>(cnt, aoff);
  k_build<<<NTOK / 256, 256, 0, stream>>>(tki, tkw, aoff, cur, stok, tslot);
  k_gather<<<(NSLOTP * D_ / 8) / 256, 256, 0, stream>>>(x, stok, Xg);
  k_transpose<<<dim3(F_ / 64, D_ / 64, E_), 256, 0, stream>>>(w1, w1t, D_, F_);
  k_transpose<<<dim3(D_ / 64, F_ / 64, E_), 256, 0, stream>>>(w2, w2t, F_, D_);
  k_gemm<D_, F_, 0><<<(F_ / 128) * (NSLOTP / 128), 256, 0, stream>>>(
      Xg, w1t, b1, aoff, H, nullptr);
  k_gemm<F_, D_, 1><<<(D_ / 128) * (NSLOTP / 128), 256, 0, stream>>>(
      H, w2t, b2, aoff, nullptr, Eout);
  k_combine<<<NTOK * (D_ / 4) / 256, 256, 0, stream>>>(Eout, tslot, tkw, out);
}

// Round 3
// 232.032 us; speedup vs baseline: 1.7691x; 1.5081x over previous
//
#include <hip/hip_runtime.h>
#include <math.h>

typedef __bf16 bf16x8 __attribute__((ext_vector_type(8)));
typedef float f32x4 __attribute__((ext_vector_type(4)));

#define B_ 4
#define S_ 1024
#define D_ 768
#define F_ 3072
#define E_ 8
#define NTOK 4096
#define NSLOTP 9216   // 8192 slots + per-expert pad to 128

__device__ __forceinline__ void gload_lds16(const void* g, void* s) {
  __builtin_amdgcn_global_load_lds((const __attribute__((address_space(1))) void*)g,
                                   (__attribute__((address_space(3))) void*)s, 16, 0, 0);
}

__device__ __forceinline__ float gelu_f(float v) {
  float u = v * (0.7978845608f + 0.0356774081f * v * v);
  float t = 1.f - 2.f / (1.f + __expf(2.f * u));   // tanh(u) with correct +/-inf limits
  return 0.5f * v * (1.f + t);
}

// ---------------- router: fp32 logits, softmax, top-2, renorm (NO atomics) ----------------
__global__ __launch_bounds__(256) void k_router(const float* __restrict__ x,
    const float* __restrict__ wr, int* __restrict__ tki, float* __restrict__ tkw) {
  int wid = threadIdx.x >> 6, lane = threadIdx.x & 63;
  int t = blockIdx.x * 4 + wid;
  const float* xp = x + (size_t)t * D_;
  float pa[E_];
#pragma unroll
  for (int e = 0; e < E_; ++e) pa[e] = 0.f;
#pragma unroll
  for (int it = 0; it < D_ / 64; ++it) {
    int d = it * 64 + lane;
    float xv = xp[d];
    const float4* wp = (const float4*)(wr + (size_t)d * E_);
    float4 a = wp[0], b = wp[1];
    pa[0] += xv * a.x; pa[1] += xv * a.y; pa[2] += xv * a.z; pa[3] += xv * a.w;
    pa[4] += xv * b.x; pa[5] += xv * b.y; pa[6] += xv * b.z; pa[7] += xv * b.w;
  }
#pragma unroll
  for (int e = 0; e < E_; ++e) {
    float v = pa[e];
    for (int off = 32; off; off >>= 1) v += __shfl_xor(v, off);
    pa[e] = v;
  }
  if (lane == 0) {
    float m = pa[0];
#pragma unroll
    for (int e = 1; e < E_; ++e) m = fmaxf(m, pa[e]);
    float p[E_], s = 0.f;
#pragma unroll
    for (int e = 0; e < E_; ++e) { p[e] = expf(pa[e] - m); s += p[e]; }
#pragma unroll
    for (int e = 0; e < E_; ++e) p[e] = p[e] / s;
    int i0 = 0; float b0 = p[0];
#pragma unroll
    for (int e = 1; e < E_; ++e) if (p[e] > b0) { b0 = p[e]; i0 = e; }
    int i1 = -1; float b1v = -1.f;
#pragma unroll
    for (int e = 0; e < E_; ++e) if (e != i0 && p[e] > b1v) { b1v = p[e]; i1 = e; }
    float den = b0 + b1v + 1e-8f;
    tki[t * 2] = i0; tki[t * 2 + 1] = i1;
    tkw[t * 2] = b0 / den; tkw[t * 2 + 1] = b1v / den;
  }
}

// ---- single-block routing: histogram -> scan -> aligned offsets -> ordered slots ----
__global__ __launch_bounds__(256) void k_route_all(const int* __restrict__ tki,
    int* __restrict__ stok, int* __restrict__ tslot, int* __restrict__ aoff) {
  __shared__ int cl[256][E_];
  __shared__ int tot[E_];
  __shared__ int aoffA[E_ + 1];
  int tid = threadIdx.x;
  // init stok = -1 (pad rows stay -1 -> gather writes zeros)
  for (int i = tid; i < NSLOTP; i += 256) stok[i] = -1;
#pragma unroll
  for (int e = 0; e < E_; ++e) cl[tid][e] = 0;
  int t0 = tid * (NTOK / 256);
#pragma unroll
  for (int i = 0; i < NTOK / 256; ++i) {
    cl[tid][tki[(t0 + i) * 2]]++;
    cl[tid][tki[(t0 + i) * 2 + 1]]++;
  }
  __syncthreads();
  if (tid < E_) {            // exclusive scan per expert column
    int run = 0;
    for (int i = 0; i < 256; ++i) { int v = cl[i][tid]; cl[i][tid] = run; run += v; }
    tot[tid] = run;
  }
  __syncthreads();
  if (tid == 0) {
    int a = 0; aoffA[0] = 0; aoff[0] = 0;
    for (int e = 0; e < E_; ++e) { a += ((tot[e] + 127) >> 7) << 7; aoffA[e + 1] = a; aoff[e + 1] = a; }
  }
  __syncthreads();
#pragma unroll
  for (int i = 0; i < NTOK / 256; ++i) {
    int t = t0 + i;
#pragma unroll
    for (int k = 0; k < 2; ++k) {
      int e = tki[t * 2 + k];
      int pos = aoffA[e] + cl[tid][e];
      cl[tid][e]++;
      stok[pos] = t;
      tslot[t * 2 + k] = pos;
    }
  }
}

// -------- gather x rows into bf16 slot matrix (zeros for padding) --------
__global__ __launch_bounds__(256) void k_gather(const float* __restrict__ x,
    const int* __restrict__ stok, __bf16* __restrict__ Xg) {
  int i8 = blockIdx.x * 256 + threadIdx.x;
  int flat = i8 * 8;
  int row = flat / D_;
  int col = flat - row * D_;
  int tok = stok[row];
  bf16x8 v;
  if (tok >= 0) {
    const float4* s = (const float4*)(x + (size_t)tok * D_ + col);
    float4 a = s[0], b = s[1];
    v[0] = (__bf16)a.x; v[1] = (__bf16)a.y; v[2] = (__bf16)a.z; v[3] = (__bf16)a.w;
    v[4] = (__bf16)b.x; v[5] = (__bf16)b.y; v[6] = (__bf16)b.z; v[7] = (__bf16)b.w;
  } else {
#pragma unroll
    for (int k = 0; k < 8; ++k) v[k] = (__bf16)0.f;
  }
  *(bf16x8*)(Xg + (size_t)flat) = v;
}

// -------- fp32 [R][C] -> bf16 [C][R] per expert --------
__global__ __launch_bounds__(256) void k_transpose(const float* __restrict__ in,
    __bf16* __restrict__ outp, int R, int C) {
  __shared__ float Ts[64][65];
  int e = blockIdx.z;
  int r0 = blockIdx.y * 64, c0 = blockIdx.x * 64;
  const float* ip = in + (size_t)e * R * C;
  int lr = threadIdx.x >> 4;
  int lc = (threadIdx.x & 15) * 4;
#pragma unroll
  for (int it = 0; it < 4; ++it) {
    int r = lr + it * 16;
    float4 v = *(const float4*)(ip + (size_t)(r0 + r) * C + c0 + lc);
    Ts[r][lc] = v.x; Ts[r][lc + 1] = v.y; Ts[r][lc + 2] = v.z; Ts[r][lc + 3] = v.w;
  }
  __syncthreads();
  int rr = (threadIdx.x & 7) * 8;
  int cc = threadIdx.x >> 3;
  __bf16* op = outp + (size_t)e * R * C + r0 + rr;
#pragma unroll
  for (int it = 0; it < 2; ++it) {
    int c = cc + it * 32;
    bf16x8 v;
#pragma unroll
    for (int i = 0; i < 8; ++i) v[i] = (__bf16)Ts[rr + i][c];
    *(bf16x8*)(op + (size_t)(c0 + c) * R) = v;
  }
}

// -------- grouped GEMM: 128x256 tile, BK=32, 8 waves (2M x 4N of 64x64) --------
// MODE 0: H = gelu(Xg @ w1t^T + b1)        [NSLOTP][F]
// MODE 1: Eout = H @ w2t^T + b2  (fp32)    [NSLOTP][D]
template<int K, int N, int MODE>
__global__ __launch_bounds__(512) void k_gemm(
    const __bf16* __restrict__ A, const __bf16* __restrict__ Bt,
    const float* __restrict__ bias, const int* __restrict__ aoff,
    __bf16* __restrict__ Hout, float* __restrict__ Eout) {
  __shared__ __align__(16) __bf16 Al[128 * 32];
  __shared__ __align__(16) __bf16 Bl[256 * 32];
  constexpr int NB = N / 256;
  constexpr int NMB = NSLOTP / 128;
  constexpr int NWG = NB * NMB;
  int bswz = (blockIdx.x & 7) * (NWG / 8) + (blockIdx.x >> 3);   // XCD-contiguous chunks
  int mb = bswz % NMB, nb = bswz / NMB;                          // mb-fast: B-panels stay L2-hot
  int row0 = mb * 128;
  if (row0 >= aoff[E_]) return;
  int e = 0;
#pragma unroll
  for (int q = 0; q < E_; ++q) if (row0 >= aoff[q + 1]) e = q + 1;
  const __bf16* Bp = Bt + (size_t)e * D_ * F_;
  int tid = threadIdx.x, w = tid >> 6, l = tid & 63;
  int lr = l >> 2, ls = l & 3;      // staging lane -> row-in-16 / 16B slot
  int fr = l & 15, fg = l >> 4;     // fragment lane -> row-col / k-group
  f32x4 acc[4][4] = {};
  int wrow = (w >> 2) * 64, wcol = (w & 3) * 64;
  for (int kt = 0; kt < K / 32; ++kt) {
    int k0 = kt * 32;
    {
      int rlA = w * 16 + lr;                       // A: 128 rows, 1 op/wave
      int sA = ls ^ ((rlA >> 1) & 3);
      gload_lds16(A + (size_t)(row0 + rlA) * K + k0 + sA * 8, Al + w * 512);
#pragma unroll
      for (int q = 0; q < 2; ++q) {                // B: 256 rows, 2 ops/wave
        int rlB = w * 32 + q * 16 + lr;
        int sB = ls ^ ((rlB >> 1) & 3);
        gload_lds16(Bp + (size_t)(nb * 256 + rlB) * K + k0 + sB * 8, Bl + (w * 2 + q) * 512);
      }
    }
    __syncthreads();
    bf16x8 af[4], bfr[4];
#pragma unroll
    for (int i = 0; i < 4; ++i) {
      int rl = wrow + i * 16 + fr;
      af[i] = *(const bf16x8*)(Al + rl * 32 + ((fg ^ ((rl >> 1) & 3)) << 3));
    }
#pragma unroll
    for (int j = 0; j < 4; ++j) {
      int nl = wcol + j * 16 + fr;
      bfr[j] = *(const bf16x8*)(Bl + nl * 32 + ((fg ^ ((nl >> 1) & 3)) << 3));
    }
#pragma unroll
    for (int i = 0; i < 4; ++i)
#pragma unroll
      for (int j = 0; j < 4; ++j)
        acc[i][j] = __builtin_amdgcn_mfma_f32_16x16x32_bf16(af[i], bfr[j], acc[i][j], 0, 0, 0);
    __syncthreads();
  }
  if constexpr (MODE == 0) {
#pragma unroll
    for (int j = 0; j < 4; ++j) {
      int col = nb * 256 + wcol + j * 16 + fr;
      float bv = bias[e * N + col];
#pragma unroll
      for (int i = 0; i < 4; ++i) {
#pragma unroll
        for (int r = 0; r < 4; ++r) {
          int row = row0 + wrow + i * 16 + fg * 4 + r;
          Hout[(size_t)row * N + col] = (__bf16)gelu_f(acc[i][j][r] + bv);
        }
      }
    }
  } else {
#pragma unroll
    for (int j = 0; j < 4; ++j) {
      int col = nb * 256 + wcol + j * 16 + fr;
      float bv = bias[e * N + col];
#pragma unroll
      for (int i = 0; i < 4; ++i) {
#pragma unroll
        for (int r = 0; r < 4; ++r) {
          int row = row0 + wrow + i * 16 + fg * 4 + r;
          Eout[(size_t)row * N + col] = acc[i][j][r] + bv;
        }
      }
    }
  }
}

// -------- combine: out[t] = w0*Eout[s0] + w1*Eout[s1] --------
__global__ __launch_bounds__(256) void k_combine(const float* __restrict__ Eout,
    const int* __restrict__ tslot, const float* __restrict__ tkw, float* __restrict__ out) {
  int idx = blockIdx.x * 256 + threadIdx.x;
  int t = idx / (D_ / 4);
  int c4 = (idx - t * (D_ / 4)) * 4;
  int s0 = tslot[2 * t], s1 = tslot[2 * t + 1];
  float w0 = tkw[2 * t], w1 = tkw[2 * t + 1];
  float4 a = *(const float4*)(Eout + (size_t)s0 * D_ + c4);
  float4 b = *(const float4*)(Eout + (size_t)s1 * D_ + c4);
  float4 o;
  o.x = w0 * a.x + w1 * b.x; o.y = w0 * a.y + w1 * b.y;
  o.z = w0 * a.z + w1 * b.z; o.w = w0 * a.w + w1 * b.w;
  *(float4*)(out + (size_t)t * D_ + c4) = o;
}

extern "C" void kernel_launch(void* const* d_in, const int* in_sizes, int n_in,
                              void* d_out, int out_size, void* d_ws, size_t ws_size,
                              hipStream_t stream) {
  const float* x  = (const float*)d_in[0];
  const float* wr = (const float*)d_in[1];
  const float* w1 = (const float*)d_in[2];
  const float* b1 = (const float*)d_in[3];
  const float* w2 = (const float*)d_in[4];
  const float* b2 = (const float*)d_in[5];
  float* out = (float*)d_out;

  char* ws = (char*)d_ws;
  size_t o = 0;
  __bf16* w1t = (__bf16*)(ws + o); o += (size_t)E_ * D_ * F_ * 2;   // [E][F][D]; dead after GEMM1
  __bf16* w2t = (__bf16*)(ws + o); o += (size_t)E_ * D_ * F_ * 2;   // [E][D][F]
  __bf16* Xg  = (__bf16*)(ws + o); o += (size_t)NSLOTP * D_ * 2;    // [NSLOTP][D]
  __bf16* H   = (__bf16*)(ws + o); o += (size_t)NSLOTP * F_ * 2;    // [NSLOTP][F]
  int*   tki  = (int*)(ws + o);   o += (size_t)NTOK * 2 * 4;
  float* tkw  = (float*)(ws + o); o += (size_t)NTOK * 2 * 4;
  int*   stok = (int*)(ws + o);   o += (size_t)NSLOTP * 4;
  int*   tslot= (int*)(ws + o);   o += (size_t)NTOK * 2 * 4;
  int*   aoff = (int*)(ws + o);   o += 64;
  float* Eout = (float*)w1t;      // alias: w1t dead before GEMM2 writes Eout (28.3MB < 37.7MB)
  if (ws_size < o) return;

  k_router<<<NTOK / 4, 256, 0, stream>>>(x, wr, tki, tkw);
  k_route_all<<<1, 256, 0, stream>>>(tki, stok, tslot, aoff);
  k_gather<<<(NSLOTP * D_ / 8) / 256, 256, 0, stream>>>(x, stok, Xg);
  k_transpose<<<dim3(F_ / 64, D_ / 64, E_), 256, 0, stream>>>(w1, w1t, D_, F_);
  k_transpose<<<dim3(D_ / 64, F_ / 64, E_), 256, 0, stream>>>(w2, w2t, F_, D_);
  k_gemm<D_, F_, 0><<<(F_ / 256) * (NSLOTP / 128), 512, 0, stream>>>(
      Xg, w1t, b1, aoff, H, nullptr);
  k_gemm<F_, D_, 1><<<(D_ / 256) * (NSLOTP / 128), 512, 0, stream>>>(
      H, w2t, b2, aoff, nullptr, Eout);
  k_combine<<<NTOK * (D_ / 4) / 256, 256, 0, stream>>>(Eout, tslot, tkw, out);
}